// Round 3
// baseline (604.527 us; speedup 1.0000x reference)
//
#include <hip/hip_runtime.h>
#include <hip/hip_bf16.h>

typedef __bf16 bf16;
typedef __bf16 bf16x8 __attribute__((ext_vector_type(8)));
typedef float f32x4 __attribute__((ext_vector_type(4)));

#define NB   32768
#define EMB  768
#define MSUB 32
#define KC   256
#define DSUB 24

// ws layout (bytes):
//   [0,      512K )  cb_bf : bf16 [32][256][32]   d padded 24->32 with zeros
//   [1M,   2.125M)  rot_bf: bf16 [768][768]
//   [4M,     68M )  xr2   : bf16 [bt*32+m][rt(2)][lane(64)][d(8)], lg==3 zeroed

__device__ __forceinline__ bf16x8 cvt8(float4 a, float4 b) {
    bf16x8 r;
    r[0] = (bf16)a.x; r[1] = (bf16)a.y; r[2] = (bf16)a.z; r[3] = (bf16)a.w;
    r[4] = (bf16)b.x; r[5] = (bf16)b.y; r[6] = (bf16)b.z; r[7] = (bf16)b.w;
    return r;
}

// ---------------------------------------------------------------- kernel 0
__global__ __launch_bounds__(256, 4)
void pq_prep(const float* __restrict__ cb, const float* __restrict__ rot,
             bf16* __restrict__ cb_bf, bf16* __restrict__ rot_bf) {
    const int b = blockIdx.x;
    const int t = threadIdx.x;
    if (b < 288) {                       // rot: 768*768 = 589824 = 288*2048
        const int o = b * 2048 + t * 8;
        float4 a0 = *(const float4*)(rot + o);
        float4 a1 = *(const float4*)(rot + o + 4);
        *(bf16x8*)(rot_bf + o) = cvt8(a0, a1);
    } else {                             // cb padded: 32*256*32 = 262144 = 128*2048
        const int o  = (b - 288) * 2048 + t * 8;
        const int m  = o >> 13;          // /(256*32)
        const int k  = (o >> 5) & 255;
        const int d0 = o & 31;           // 0,8,16,24
        bf16x8 v;
        if (d0 < DSUB) {
            const float* cp = cb + (size_t)(m * KC + k) * DSUB + d0;
            v = cvt8(*(const float4*)cp, *(const float4*)(cp + 4));
        } else {
            const float4 fz = {0.f, 0.f, 0.f, 0.f};
            v = cvt8(fz, fz);
        }
        *(bf16x8*)(cb_bf + o) = v;
    }
}

// ---------------------------------------------------------------- kernel 1
__global__ __launch_bounds__(512, 4)
void pq_rot(const float* __restrict__ x, const bf16* __restrict__ rot_bf,
            bf16* __restrict__ xr2) {
    // granule layout [e/8 (96)][row (32)][slot (8)] = 48 KiB; holds x (bf16)
    // during the GEMM, then is overwritten with xr for the epilogue.
    __shared__ bf16 g_lds[96 * 32 * 8];

    const int tid  = threadIdx.x;
    const int w    = tid >> 6;
    const int lane = tid & 63;
    const int l15  = lane & 15;
    const int lg   = lane >> 4;
    const int rowbase = blockIdx.x * 32;

    // stage x -> bf16 granules (each element read from HBM exactly once)
    #pragma unroll
    for (int i = 0; i < 6; ++i) {
        const int oct = i * 512 + tid;
        const int row = oct & 31;
        const int e8  = oct >> 5;
        const float* xp = x + (size_t)(rowbase + row) * EMB + e8 * 8;
        *(bf16x8*)&g_lds[(e8 * 32 + row) * 8] =
            cvt8(*(const float4*)xp, *(const float4*)(xp + 4));
    }
    __syncthreads();

    // xr = x @ rot^T ; wave w owns j in [w*96, w*96+96)
    f32x4 acc[2][6];
    #pragma unroll
    for (int rt = 0; rt < 2; ++rt)
        #pragma unroll
        for (int jt = 0; jt < 6; ++jt)
            acc[rt][jt] = (f32x4){0.f, 0.f, 0.f, 0.f};

    const int jbase = w * 96;
    #pragma unroll 2
    for (int e0 = 0; e0 < EMB; e0 += 32) {
        bf16x8 afrag[2];
        #pragma unroll
        for (int rt = 0; rt < 2; ++rt)
            afrag[rt] = *(const bf16x8*)&g_lds[(((e0 >> 3) + lg) * 32 + rt * 16 + l15) * 8];
        #pragma unroll
        for (int jt = 0; jt < 6; ++jt) {
            const bf16* bp = rot_bf + (size_t)(jbase + jt * 16 + l15) * EMB + e0 + lg * 8;
            bf16x8 bfrag = *(const bf16x8*)bp;
            acc[0][jt] = __builtin_amdgcn_mfma_f32_16x16x32_bf16(afrag[0], bfrag, acc[0][jt], 0, 0, 0);
            acc[1][jt] = __builtin_amdgcn_mfma_f32_16x16x32_bf16(afrag[1], bfrag, acc[1][jt], 0, 0, 0);
        }
    }
    __syncthreads();   // done reading x granules

    // overwrite g_lds with xr granules (C-frag: col j = l15, rows lg*4+r)
    #pragma unroll
    for (int rt = 0; rt < 2; ++rt) {
        #pragma unroll
        for (int jt = 0; jt < 6; ++jt) {
            const int j    = jbase + jt * 16 + l15;
            const int gE   = j >> 3;
            const int slot = j & 7;
            #pragma unroll
            for (int r = 0; r < 4; ++r)
                g_lds[(gE * 32 + rt * 16 + lg * 4 + r) * 8 + slot] = (bf16)acc[rt][jt][r];
        }
    }
    __syncthreads();

    // epilogue: coalesced xr2 chunks; wave w owns m = w*4..w*4+3
    const float4 fz = {0.f, 0.f, 0.f, 0.f};
    const bf16x8 bzero = cvt8(fz, fz);
    #pragma unroll
    for (int mm = 0; mm < 4; ++mm) {
        const int m = w * 4 + mm;
        const size_t c = (size_t)(blockIdx.x * 32 + m);
        #pragma unroll
        for (int rt = 0; rt < 2; ++rt) {
            bf16x8 v = bzero;
            if (lg < 3)    // granule 3m+lg holds e = 24m + lg*8 + d
                v = *(const bf16x8*)&g_lds[((3 * m + lg) * 32 + rt * 16 + l15) * 8];
            *(bf16x8*)(xr2 + (c * 2 + rt) * 512 + lane * 8) = v;
        }
    }
}

// ---------------------------------------------------------------- kernel 2
__global__ __launch_bounds__(512, 4)
void pq_scores(const bf16* __restrict__ xr2, const bf16* __restrict__ cb_bf,
               float* __restrict__ out) {
    const int tid  = threadIdx.x;
    const int w    = tid >> 6;
    const int lane = tid & 63;
    const int l15  = lane & 15;
    const int lg   = lane >> 4;
    const int rowbase = blockIdx.x * 32;

    // wave w: rows [rowbase, rowbase+32), m in {w*4..w*4+3}, all 256 k.
    // No LDS, no barriers; each (row,m) 1 KiB line is written entirely by
    // this wave within one kt-loop (L2 merges the 64 B segments).
    #pragma unroll 1
    for (int mm = 0; mm < 4; ++mm) {
        const int m = w * 4 + mm;
        const size_t c = (size_t)(blockIdx.x * 32 + m);
        bf16x8 a2[2];
        a2[0] = *(const bf16x8*)(xr2 + (c * 2 + 0) * 512 + lane * 8);
        a2[1] = *(const bf16x8*)(xr2 + (c * 2 + 1) * 512 + lane * 8);
        const bf16* cbm = cb_bf + (size_t)m * (KC * 32);
        float* outm = out + ((size_t)rowbase * MSUB + m) * KC;
        #pragma unroll 4
        for (int kt = 0; kt < 16; ++kt) {
            bf16x8 bfrag = *(const bf16x8*)(cbm + (kt * 16 + l15) * 32 + lg * 8);
            #pragma unroll
            for (int rt = 0; rt < 2; ++rt) {
                f32x4 cc = __builtin_amdgcn_mfma_f32_16x16x32_bf16(
                    a2[rt], bfrag, (f32x4){0.f, 0.f, 0.f, 0.f}, 0, 0, 0);
                #pragma unroll
                for (int r = 0; r < 4; ++r) {
                    const int rr = rt * 16 + lg * 4 + r;   // row within block
                    outm[(size_t)rr * (MSUB * KC) + kt * 16 + l15] = cc[r];
                }
            }
        }
    }
}

extern "C" void kernel_launch(void* const* d_in, const int* in_sizes, int n_in,
                              void* d_out, int out_size, void* d_ws, size_t ws_size,
                              hipStream_t stream) {
    const float* x   = (const float*)d_in[0];   // [32768, 768]
    const float* cbk = (const float*)d_in[1];   // [32, 256, 24]
    const float* rot = (const float*)d_in[2];   // [768, 768]
    float* out = (float*)d_out;                 // [32768, 32, 256]

    char* ws = (char*)d_ws;
    bf16* cb_bf  = (bf16*)(ws);
    bf16* rot_bf = (bf16*)(ws + (1u << 20));
    bf16* xr2    = (bf16*)(ws + (4u << 20));

    hipLaunchKernelGGL(pq_prep,   dim3(416),  dim3(256), 0, stream, cbk, rot, cb_bf, rot_bf);
    hipLaunchKernelGGL(pq_rot,    dim3(1024), dim3(512), 0, stream, x, rot_bf, xr2);
    hipLaunchKernelGGL(pq_scores, dim3(1024), dim3(512), 0, stream, xr2, cb_bf, out);
}